// Round 1
// baseline (554.312 us; speedup 1.0000x reference)
//
#include <hip/hip_runtime.h>
#include <hip/hip_bf16.h>

// Grouped experts GEMM: out[t, o] = sum_k input[t,k] * weight[e(t), o, k] + bias[e(t), o]
// E=8, T=32768, DIN(K)=1024, DOUT(N)=4096, counts[e] == 4096 each.
//
// Strategy: f32 -> bf16 convert pass into d_ws (if it fits), then m97-style
// 128x128 bf16 MFMA GEMM with BK=64, global_load_lds(16B), XOR-swizzled LDS
// (swizzle applied on the pre-swizzled GLOBAL source; LDS dest stays linear),
// fused bias epilogue. Fallback (ws too small): same tile structure but
// reg-staged f32 load + cvt + ds_write into a padded (144B-row) LDS layout.

#define DEVFN __device__ __forceinline__

constexpr int E_    = 8;
constexpr int T_    = 32768;
constexpr int DIN_  = 1024;   // K
constexpr int DOUT_ = 4096;   // N
constexpr int BM = 128, BN = 128, BK = 64;
constexpr int KTILES = DIN_ / BK;        // 16
constexpr int MTILES = (T_ / E_) / BM;   // 32
constexpr int NTILES = DOUT_ / BN;       // 32

typedef __attribute__((ext_vector_type(8))) __bf16 bf16x8;   // MFMA A/B frag (4 VGPR)
typedef __attribute__((ext_vector_type(4))) float  f32x4;    // MFMA C/D frag
typedef __attribute__((ext_vector_type(8))) short  s16x8;    // 16B of bf16 bits

DEVFN unsigned short f2bf(float x) {
  // round-to-nearest-even f32 -> bf16 (inputs are finite)
  unsigned u = __builtin_bit_cast(unsigned, x);
  u += 0x7fffu + ((u >> 16) & 1u);
  return (unsigned short)(u >> 16);
}

// Robust expert-offset: harness docs say integer inputs arrive as int32, but
// hedge against int64 by checking that int32-view counts sum to T.
DEVFN long long expert_offset(const void* cnts, int e) {
  const int* c32 = (const int*)cnts;
  long long s = 0;
  for (int i = 0; i < E_; ++i) s += c32[i];
  if (s == (long long)T_) {
    long long o = 0;
    for (int i = 0; i < e; ++i) o += c32[i];
    return o;
  }
  const long long* c64 = (const long long*)cnts;
  long long o = 0;
  for (int i = 0; i < e; ++i) o += c64[i];
  return o;
}

__global__ __launch_bounds__(256) void cvt_kernel(const float* __restrict__ in,
                                                  unsigned short* __restrict__ out,
                                                  int n4) {
  int i = blockIdx.x * 256 + threadIdx.x;
  if (i >= n4) return;
  const float4 f = reinterpret_cast<const float4*>(in)[i];
  ushort4 h;
  h.x = f2bf(f.x); h.y = f2bf(f.y); h.z = f2bf(f.z); h.w = f2bf(f.w);
  reinterpret_cast<ushort4*>(out)[i] = h;
}

// MODE 0: A/B are bf16 (pre-converted in ws), stage via global_load_lds with
//         pre-swizzled global source; LDS rows 128B, read swizzle c^(r&7).
// MODE 1: A/B are f32 (original inputs), reg-stage + cvt + ds_write into
//         padded LDS rows (144B) -> conflict-free without swizzle.
template <int MODE>
__global__ __launch_bounds__(256) void gemm_kernel(const void* __restrict__ Aop,
                                                   const void* __restrict__ Bop,
                                                   const float* __restrict__ bias,
                                                   const void* __restrict__ counts,
                                                   float* __restrict__ out) {
  constexpr int RS    = (MODE == 0) ? 128 : 144;  // LDS row stride in bytes
  constexpr int BBASE = BM * RS;                  // B tile base inside LDS
  __shared__ __align__(16) unsigned char lds[2 * BM * RS];

  const int tid  = threadIdx.x;
  const int lane = tid & 63;
  const int wid  = tid >> 6;
  const int wm = wid >> 1, wn = wid & 1;   // 2x2 wave grid over 128x128

  const int bid = blockIdx.x;
  const int e  = bid >> 10;          // 1024 tiles per expert (32x32)
  const int t  = bid & 1023;
  const int tm = t >> 5, tn = t & 31;

  const long long off = expert_offset(counts, e);
  const long long rowA0 = off + (long long)tm * BM;
  const int n0 = tn * BN;

  f32x4 acc[4][4] = {};   // 64x64 per wave = 4x4 fragments of 16x16

  auto ldsoff = [](int r, int c) -> int {   // byte offset of logical granule (r, c)
    if constexpr (MODE == 0) return r * 128 + (((c ^ (r & 7)) << 4));
    else                     return r * 144 + (c << 4);
  };

  for (int kt = 0; kt < KTILES; ++kt) {
    const int k0 = kt * BK;

    if constexpr (MODE == 0) {
      const __hip_bfloat16* A = (const __hip_bfloat16*)Aop;
      const __hip_bfloat16* B = (const __hip_bfloat16*)Bop;
#pragma unroll
      for (int rd = 0; rd < 8; ++rd) {
        const int chunk = rd * 256 + tid;        // 16B granule id; 0..1023=A, 1024..2047=B
        const int c2 = chunk & 1023;
        const int r  = c2 >> 3;
        const int cl = (c2 & 7) ^ (r & 7);       // pre-swizzle the global source
        const __hip_bfloat16* src =
            (rd < 4) ? (A + (rowA0 + r) * (long long)DIN_ + (k0 + cl * 8))
                     : (B + ((long long)(e * DOUT_ + n0 + r)) * DIN_ + (k0 + cl * 8));
        __builtin_amdgcn_global_load_lds(
            (const __attribute__((address_space(1))) void*)src,
            (__attribute__((address_space(3))) void*)(&lds[chunk << 4]), 16, 0, 0);
      }
    } else {
      const float* Af = (const float*)Aop;
      const float* Bf = (const float*)Bop;
#pragma unroll
      for (int rd = 0; rd < 8; ++rd) {
        const int chunk = rd * 256 + tid;
        const int c2 = chunk & 1023;
        const int r  = c2 >> 3;
        const int c  = c2 & 7;
        const float* src =
            (rd < 4) ? (Af + (rowA0 + r) * (long long)DIN_ + (k0 + c * 8))
                     : (Bf + ((long long)(e * DOUT_ + n0 + r)) * DIN_ + (k0 + c * 8));
        const float4 f0 = *reinterpret_cast<const float4*>(src);
        const float4 f1 = *reinterpret_cast<const float4*>(src + 4);
        s16x8 v;
        v[0] = (short)f2bf(f0.x); v[1] = (short)f2bf(f0.y);
        v[2] = (short)f2bf(f0.z); v[3] = (short)f2bf(f0.w);
        v[4] = (short)f2bf(f1.x); v[5] = (short)f2bf(f1.y);
        v[6] = (short)f2bf(f1.z); v[7] = (short)f2bf(f1.w);
        *reinterpret_cast<s16x8*>(&lds[((rd < 4) ? 0 : BBASE) + r * 144 + (c << 4)]) = v;
      }
    }
    __syncthreads();

#pragma unroll
    for (int kk = 0; kk < 2; ++kk) {           // two 16x16x32 K-steps per BK=64
      const int rsel = lane & 15;
      const int csel = kk * 4 + (lane >> 4);   // 16B granule index along K
      bf16x8 af[4], bfr[4];
#pragma unroll
      for (int mf = 0; mf < 4; ++mf) {
        const int r = wm * 64 + mf * 16 + rsel;
        af[mf] = *reinterpret_cast<const bf16x8*>(&lds[ldsoff(r, csel)]);
      }
#pragma unroll
      for (int nf = 0; nf < 4; ++nf) {
        const int r = wn * 64 + nf * 16 + rsel;
        bfr[nf] = *reinterpret_cast<const bf16x8*>(&lds[BBASE + ldsoff(r, csel)]);
      }
#pragma unroll
      for (int mf = 0; mf < 4; ++mf)
#pragma unroll
        for (int nf = 0; nf < 4; ++nf)
          acc[mf][nf] = __builtin_amdgcn_mfma_f32_16x16x32_bf16(af[mf], bfr[nf],
                                                                acc[mf][nf], 0, 0, 0);
    }
    __syncthreads();
  }

  // Epilogue: C/D layout (m89-verified): col = lane&15, row = (lane>>4)*4 + reg
  const long long orow0 = off + (long long)tm * BM + wm * 64;
  const int ocol0 = n0 + wn * 64;
  const int rlo = (lane >> 4) * 4;
  const int c15 = lane & 15;
#pragma unroll
  for (int nf = 0; nf < 4; ++nf) {
    const int n = ocol0 + nf * 16 + c15;
    const float bv = bias[e * DOUT_ + n];
#pragma unroll
    for (int mf = 0; mf < 4; ++mf) {
      const long long mrow = orow0 + mf * 16 + rlo;
#pragma unroll
      for (int j = 0; j < 4; ++j) {
        out[(mrow + j) * (long long)DOUT_ + n] = acc[mf][nf][j] + bv;
      }
    }
  }
}

extern "C" void kernel_launch(void* const* d_in, const int* in_sizes, int n_in,
                              void* d_out, int out_size, void* d_ws, size_t ws_size,
                              hipStream_t stream) {
  const float* input  = (const float*)d_in[0];
  const float* weight = (const float*)d_in[1];
  const float* bias   = (const float*)d_in[2];
  const void*  counts = (const void*)d_in[3];
  float* out = (float*)d_out;

  const size_t nA = (size_t)T_ * DIN_;           // 33554432 elements
  const size_t nW = (size_t)E_ * DOUT_ * DIN_;   // 33554432 elements
  const size_t need = (nA + nW) * sizeof(unsigned short);  // 128 MiB

  const dim3 blk(256);
  const dim3 ggrid(E_ * MTILES * NTILES);        // 8192 workgroups

  if (ws_size >= need) {
    unsigned short* wa = (unsigned short*)d_ws;
    unsigned short* wb = wa + nA;
    cvt_kernel<<<dim3((unsigned)(nA / 4 / 256)), blk, 0, stream>>>(input, wa, (int)(nA / 4));
    cvt_kernel<<<dim3((unsigned)(nW / 4 / 256)), blk, 0, stream>>>(weight, wb, (int)(nW / 4));
    gemm_kernel<0><<<ggrid, blk, 0, stream>>>((const void*)wa, (const void*)wb, bias, counts, out);
  } else {
    gemm_kernel<1><<<ggrid, blk, 0, stream>>>((const void*)input, (const void*)weight, bias, counts, out);
  }
}

// Round 2
// 403.761 us; speedup vs baseline: 1.3729x; 1.3729x over previous
//
#include <hip/hip_runtime.h>
#include <hip/hip_bf16.h>

// Grouped experts GEMM: out[t, o] = sum_k input[t,k] * weight[e(t), o, k] + bias[e(t), o]
// E=8, T=32768, DIN(K)=1024, DOUT(N)=4096.
//
// Round 2: 256x256 8-phase schedule (T1 XCD swizzle + T2 LDS swizzle +
// T3/T4 8-phase counted-vmcnt + T5 setprio). f32->bf16 cvt pass into ws,
// then the pipelined bf16 MFMA GEMM with fused bias epilogue.

#define DEVFN __device__ __forceinline__

constexpr int E_    = 8;
constexpr int T_    = 32768;
constexpr int DIN_  = 1024;   // K
constexpr int DOUT_ = 4096;   // N

typedef __attribute__((ext_vector_type(8))) __bf16 bf16x8;   // MFMA A/B frag (4 VGPR)
typedef __attribute__((ext_vector_type(4))) float  f32x4;    // MFMA C/D frag
typedef __attribute__((ext_vector_type(8))) short  s16x8;

DEVFN unsigned short f2bf(float x) {
  unsigned u = __builtin_bit_cast(unsigned, x);
  u += 0x7fffu + ((u >> 16) & 1u);
  return (unsigned short)(u >> 16);
}

DEVFN long long expert_offset(const void* cnts, int e) {
  const int* c32 = (const int*)cnts;
  long long s = 0;
  for (int i = 0; i < E_; ++i) s += c32[i];
  if (s == (long long)T_) {
    long long o = 0;
    for (int i = 0; i < e; ++i) o += c32[i];
    return o;
  }
  const long long* c64 = (const long long*)cnts;
  long long o = 0;
  for (int i = 0; i < e; ++i) o += c64[i];
  return o;
}

__global__ __launch_bounds__(256) void cvt_kernel(const float* __restrict__ in,
                                                  unsigned short* __restrict__ out,
                                                  int n4) {
  int i = blockIdx.x * 256 + threadIdx.x;
  if (i >= n4) return;
  const float4 f = reinterpret_cast<const float4*>(in)[i];
  ushort4 h;
  h.x = f2bf(f.x); h.y = f2bf(f.y); h.z = f2bf(f.z); h.w = f2bf(f.w);
  reinterpret_cast<ushort4*>(out)[i] = h;
}

// ---------------------------------------------------------------------------
// 256x256 8-phase pipelined GEMM. 512 threads = 8 waves (2M x 4N).
// Per wave: 128x64 output = acc[8][4] 16x16 fragments. BK=64 (2 MFMA K-steps).
// LDS: 2 K-tile buffers x (A 32KB + B 32KB) = 128 KiB. Granule swizzle
// c ^= (r&7) applied on the pre-swizzled GLOBAL source (LDS dest linear,
// required by global_load_lds) and on the ds_read address (involution).
// Phases per K-tile: P1 (mq0,nq0: 12 ds_reads), P2 (nq1: 4), P3 (mq1: 8,
// + B-prefetch issue), P4 (A-prefetch issue). vmcnt(8) once per K-tile,
// placed BEFORE the closing barrier so all waves' DMA is landed before any
// wave reads the next buffer. Last two K-tiles peeled (vmcnt 0 / none).
// ---------------------------------------------------------------------------
__global__ __launch_bounds__(512, 2) void gemm2_kernel(const unsigned short* __restrict__ wa,
                                                       const unsigned short* __restrict__ wb,
                                                       const float* __restrict__ bias,
                                                       const void* __restrict__ counts,
                                                       float* __restrict__ out) {
  __shared__ __align__(16) unsigned char lds[2][2][32768];

  const int tid  = threadIdx.x;
  const int lane = tid & 63;
  const int wid  = tid >> 6;
  const int wm = wid >> 2, wn = wid & 3;   // 2 x 4 wave grid

  // T1: XCD-aware swizzle (nwg = 2048, divisible by 8 -> simple bijection)
  const int bid = blockIdx.x;
  const int sid = (bid & 7) * 256 + (bid >> 3);
  const int e  = sid >> 8;           // 256 tiles per expert (16 x 16)
  const int t  = sid & 255;
  const int tm = t >> 4, tn = t & 15;

  const long long off = expert_offset(counts, e);
  const unsigned short* wat = wa + (off + (long long)tm * 256) * DIN_;
  const unsigned short* wbt = wb + ((long long)(e * DOUT_ + tn * 256)) * DIN_;

  // Staging precompute (loop-invariant): 4 rounds x 512 threads x 16B per tile
  int goff[4], loff[4];
#pragma unroll
  for (int rd = 0; rd < 4; ++rd) {
    const int chunk = rd * 512 + tid;
    const int r = chunk >> 3, c = chunk & 7;
    goff[rd] = r * DIN_ + (c ^ (r & 7)) * 8;   // pre-swizzled global element offset
    loff[rd] = chunk * 16;                     // linear LDS dest
  }
  auto stage = [&](const unsigned short* g, unsigned char* l) {
#pragma unroll
    for (int rd = 0; rd < 4; ++rd)
      __builtin_amdgcn_global_load_lds(
          (const __attribute__((address_space(1))) void*)(g + goff[rd]),
          (__attribute__((address_space(3))) void*)(l + loff[rd]), 16, 0, 0);
  };

  // ds_read lane addressing: 16 rows (lane&15) x granule (kk*4 + lane>>4)
  const int rsel = lane & 15, hi = lane >> 4;
  int lp[2];
  lp[0] = rsel * 128 + (((hi)     ^ (rsel & 7)) << 4);
  lp[1] = rsel * 128 + (((4 + hi) ^ (rsel & 7)) << 4);

  bf16x8 a[4][2];        // A frags for current mq
  bf16x8 b[2][2][2];     // B frags [nq][j][kk], both nq held across phases
  f32x4  acc[8][4] = {}; // [mq*4+mf][nf]

  auto quad = [&](int am0, int q) {
#pragma unroll
    for (int mf = 0; mf < 4; ++mf)
#pragma unroll
      for (int j = 0; j < 2; ++j)
#pragma unroll
        for (int kk = 0; kk < 2; ++kk)
          acc[am0 + mf][q * 2 + j] = __builtin_amdgcn_mfma_f32_16x16x32_bf16(
              a[mf][kk], b[q][j][kk], acc[am0 + mf][q * 2 + j], 0, 0, 0);
  };

  const int abase = wm * 128 * 128;  // wave's A-row block byte offset
  const int bbase = wn * 64 * 128;   // wave's B-row block byte offset

  auto ktile = [&](unsigned char* Ab, unsigned char* Bb,
                   const unsigned short* pfa, const unsigned short* pfb,
                   bool pf, int nend) {
    // ---- P1: quadrant (mq=0, nq=0)
#pragma unroll
    for (int mf = 0; mf < 4; ++mf)
#pragma unroll
      for (int kk = 0; kk < 2; ++kk)
        a[mf][kk] = *(const bf16x8*)(Ab + abase + mf * 2048 + lp[kk]);
#pragma unroll
    for (int j = 0; j < 2; ++j)
#pragma unroll
      for (int kk = 0; kk < 2; ++kk)
        b[0][j][kk] = *(const bf16x8*)(Bb + bbase + j * 2048 + lp[kk]);
    __builtin_amdgcn_s_barrier();
    asm volatile("s_waitcnt lgkmcnt(0)" ::: "memory");
    __builtin_amdgcn_sched_barrier(0);
    __builtin_amdgcn_s_setprio(1);
    quad(0, 0);
    __builtin_amdgcn_s_setprio(0);
    __builtin_amdgcn_s_barrier();

    // ---- P2: quadrant (mq=0, nq=1)
#pragma unroll
    for (int j = 0; j < 2; ++j)
#pragma unroll
      for (int kk = 0; kk < 2; ++kk)
        b[1][j][kk] = *(const bf16x8*)(Bb + bbase + (32 + j * 16) * 128 + lp[kk]);
    __builtin_amdgcn_s_barrier();
    asm volatile("s_waitcnt lgkmcnt(0)" ::: "memory");
    __builtin_amdgcn_sched_barrier(0);
    __builtin_amdgcn_s_setprio(1);
    quad(0, 1);
    __builtin_amdgcn_s_setprio(0);
    __builtin_amdgcn_s_barrier();

    // ---- P3: quadrant (mq=1, nq=1); B region of this buffer is fully read
    //          (P1+P2) -> safe to issue next-K-tile B prefetch into it.
#pragma unroll
    for (int mf = 0; mf < 4; ++mf)
#pragma unroll
      for (int kk = 0; kk < 2; ++kk)
        a[mf][kk] = *(const bf16x8*)(Ab + abase + 8192 + mf * 2048 + lp[kk]);
    if (pf) stage(pfb, Bb);
    __builtin_amdgcn_s_barrier();
    asm volatile("s_waitcnt lgkmcnt(0)" ::: "memory");
    __builtin_amdgcn_sched_barrier(0);
    __builtin_amdgcn_s_setprio(1);
    quad(4, 1);
    __builtin_amdgcn_s_setprio(0);
    __builtin_amdgcn_s_barrier();

    // ---- P4: quadrant (mq=1, nq=0); A region fully read (P1+P3) ->
    //          issue next-K-tile A prefetch. End-of-K-tile counted vmcnt.
    if (pf) stage(pfa, Ab);
    __builtin_amdgcn_s_barrier();
    __builtin_amdgcn_sched_barrier(0);
    __builtin_amdgcn_s_setprio(1);
    quad(4, 0);
    __builtin_amdgcn_s_setprio(0);
    if (nend == 8)      asm volatile("s_waitcnt vmcnt(8)" ::: "memory");
    else if (nend == 0) asm volatile("s_waitcnt vmcnt(0)" ::: "memory");
    __builtin_amdgcn_s_barrier();
  };

  // Prologue: stage K-tiles 0 and 1; wait K-tile 0 landed (all waves), barrier.
  stage(wat,      &lds[0][0][0]);
  stage(wbt,      &lds[0][1][0]);
  stage(wat + 64, &lds[1][0][0]);
  stage(wbt + 64, &lds[1][1][0]);
  asm volatile("s_waitcnt vmcnt(8)" ::: "memory");
  __builtin_amdgcn_s_barrier();

  // Main loop: 7 iterations x 2 K-tiles, prefetching kt+2. Last pair peeled.
  for (int it = 0; it < 7; ++it) {
    const int k0 = 2 * it;
    ktile(&lds[0][0][0], &lds[0][1][0], wat + (k0 + 2) * 64, wbt + (k0 + 2) * 64, true, 8);
    ktile(&lds[1][0][0], &lds[1][1][0], wat + (k0 + 3) * 64, wbt + (k0 + 3) * 64, true, 8);
  }
  ktile(&lds[0][0][0], &lds[0][1][0], nullptr, nullptr, false, 0);
  ktile(&lds[1][0][0], &lds[1][1][0], nullptr, nullptr, false, -1);

  // Epilogue: C/D layout col = lane&15, row = (lane>>4)*4 + j (m89-verified).
  const long long orow0 = off + (long long)tm * 256 + wm * 128;
  const int ocol0 = tn * 256 + wn * 64;
  const int rlo = hi * 4;
  const int c15 = rsel;
#pragma unroll
  for (int nf = 0; nf < 4; ++nf) {
    const int ncol = ocol0 + nf * 16 + c15;
    const float bv = bias[e * DOUT_ + ncol];
#pragma unroll
    for (int am = 0; am < 8; ++am) {
      const int rl = (am >> 2) * 64 + (am & 3) * 16 + rlo;
#pragma unroll
      for (int j = 0; j < 4; ++j)
        out[(orow0 + rl + j) * (long long)DOUT_ + ncol] = acc[am][nf][j] + bv;
    }
  }
}

// ---------------------------------------------------------------------------
// Fallback (ws too small): round-1 128x128 kernel, reg-staged f32->bf16.
// ---------------------------------------------------------------------------
__global__ __launch_bounds__(256) void gemm_fb_kernel(const float* __restrict__ Af,
                                                      const float* __restrict__ Bf,
                                                      const float* __restrict__ bias,
                                                      const void* __restrict__ counts,
                                                      float* __restrict__ out) {
  constexpr int RS = 144;
  constexpr int BBASE = 128 * RS;
  __shared__ __align__(16) unsigned char lds[2 * 128 * RS];

  const int tid  = threadIdx.x;
  const int lane = tid & 63;
  const int wid  = tid >> 6;
  const int wm = wid >> 1, wn = wid & 1;

  const int bid = blockIdx.x;
  const int e  = bid >> 10;
  const int t  = bid & 1023;
  const int tm = t >> 5, tn = t & 31;

  const long long off = expert_offset(counts, e);
  const long long rowA0 = off + (long long)tm * 128;
  const int n0 = tn * 128;

  f32x4 acc[4][4] = {};

  for (int kt = 0; kt < DIN_ / 64; ++kt) {
    const int k0 = kt * 64;
#pragma unroll
    for (int rd = 0; rd < 8; ++rd) {
      const int chunk = rd * 256 + tid;
      const int c2 = chunk & 1023;
      const int r  = c2 >> 3;
      const int c  = c2 & 7;
      const float* src =
          (rd < 4) ? (Af + (rowA0 + r) * (long long)DIN_ + (k0 + c * 8))
                   : (Bf + ((long long)(e * DOUT_ + n0 + r)) * DIN_ + (k0 + c * 8));
      const float4 f0 = *reinterpret_cast<const float4*>(src);
      const float4 f1 = *reinterpret_cast<const float4*>(src + 4);
      s16x8 v;
      v[0] = (short)f2bf(f0.x); v[1] = (short)f2bf(f0.y);
      v[2] = (short)f2bf(f0.z); v[3] = (short)f2bf(f0.w);
      v[4] = (short)f2bf(f1.x); v[5] = (short)f2bf(f1.y);
      v[6] = (short)f2bf(f1.z); v[7] = (short)f2bf(f1.w);
      *reinterpret_cast<s16x8*>(&lds[((rd < 4) ? 0 : BBASE) + r * RS + (c << 4)]) = v;
    }
    __syncthreads();
#pragma unroll
    for (int kk = 0; kk < 2; ++kk) {
      const int rs = lane & 15;
      const int cs = kk * 4 + (lane >> 4);
      bf16x8 af[4], bfr[4];
#pragma unroll
      for (int mf = 0; mf < 4; ++mf)
        af[mf] = *reinterpret_cast<const bf16x8*>(&lds[(wm * 64 + mf * 16 + rs) * RS + (cs << 4)]);
#pragma unroll
      for (int nf = 0; nf < 4; ++nf)
        bfr[nf] = *reinterpret_cast<const bf16x8*>(&lds[BBASE + (wn * 64 + nf * 16 + rs) * RS + (cs << 4)]);
#pragma unroll
      for (int mf = 0; mf < 4; ++mf)
#pragma unroll
        for (int nf = 0; nf < 4; ++nf)
          acc[mf][nf] = __builtin_amdgcn_mfma_f32_16x16x32_bf16(af[mf], bfr[nf], acc[mf][nf], 0, 0, 0);
    }
    __syncthreads();
  }

  const long long orow0 = off + (long long)tm * 128 + wm * 64;
  const int ocol0 = n0 + wn * 64;
  const int rlo = (lane >> 4) * 4;
  const int c15 = lane & 15;
#pragma unroll
  for (int nf = 0; nf < 4; ++nf) {
    const int n = ocol0 + nf * 16 + c15;
    const float bv = bias[e * DOUT_ + n];
#pragma unroll
    for (int mf = 0; mf < 4; ++mf) {
      const long long mrow = orow0 + mf * 16 + rlo;
#pragma unroll
      for (int j = 0; j < 4; ++j)
        out[(mrow + j) * (long long)DOUT_ + n] = acc[mf][nf][j] + bv;
    }
  }
}

extern "C" void kernel_launch(void* const* d_in, const int* in_sizes, int n_in,
                              void* d_out, int out_size, void* d_ws, size_t ws_size,
                              hipStream_t stream) {
  const float* input  = (const float*)d_in[0];
  const float* weight = (const float*)d_in[1];
  const float* bias   = (const float*)d_in[2];
  const void*  counts = (const void*)d_in[3];
  float* out = (float*)d_out;

  const size_t nA = (size_t)T_ * DIN_;
  const size_t nW = (size_t)E_ * DOUT_ * DIN_;
  const size_t need = (nA + nW) * sizeof(unsigned short);

  if (ws_size >= need) {
    unsigned short* wa = (unsigned short*)d_ws;
    unsigned short* wb = wa + nA;
    cvt_kernel<<<dim3((unsigned)(nA / 4 / 256)), dim3(256), 0, stream>>>(input, wa, (int)(nA / 4));
    cvt_kernel<<<dim3((unsigned)(nW / 4 / 256)), dim3(256), 0, stream>>>(weight, wb, (int)(nW / 4));
    gemm2_kernel<<<dim3(2048), dim3(512), 0, stream>>>(wa, wb, bias, counts, out);
  } else {
    gemm_fb_kernel<<<dim3(E_ * 32 * 32), dim3(256), 0, stream>>>(input, weight, bias, counts, out);
  }
}